// Round 6
// baseline (659.311 us; speedup 1.0000x reference)
//
#include <hip/hip_runtime.h>
#include <hip/hip_bf16.h>
#include <stdint.h>

// EncoderLayer on MI355X: bf16 MFMA GEMMs + fp32 softmax/LN epilogues.
// Pipeline: prep(convert/transpose) -> fused QKV (Q pre-scaled 1/8) -> Vt ->
//           flash(scores+softmax+PV, writes exact attn; BARRIER-FREE) ->
//           Wo+resid -> LN1 -> FFN1(relu) -> FFN2+resid -> LN2.
// GEMM: global_load_lds width=16 staging (m97), T1 XCD swizzle (grids %8==0).
// Flash: 1 wave/block, K/V read direct from global (L2-resident per head;
//        m169: never LDS-stage L2-fit data), per-lane online stats, only
//        wave-private 4KB sP in LDS (intra-wave fence, no __syncthreads).

using bf16_t  = __hip_bfloat16;
using short8  = __attribute__((ext_vector_type(8))) short;
using short4v = __attribute__((ext_vector_type(4))) short;
using f32x4   = __attribute__((ext_vector_type(4))) float;

#define DEV static __device__ __forceinline__

DEV short bfbits(float f) {
  bf16_t h = __float2bfloat16(f);
  union { bf16_t h; short s; } u; u.h = h; return u.s;
}

// async global->LDS, 16 bytes per lane; lds must be wave-uniform, HW writes
// lds + lane*16 (cdna_hip_programming.md §5: width=16 = 874 TF lever).
DEV void gload_lds16(const bf16_t* g, bf16_t* lds) {
  __builtin_amdgcn_global_load_lds(
      (const __attribute__((address_space(1))) void*)g,
      (__attribute__((address_space(3))) void*)lds, 16, 0, 0);
}

// ---------------- elementwise fp32 -> bf16 (4 elems/thread) ----------------
__global__ __launch_bounds__(256) void k_f32_to_bf16(const float* __restrict__ in,
                                                     bf16_t* __restrict__ out) {
  size_t i = ((size_t)blockIdx.x * 256 + threadIdx.x) * 4;
  f32x4 x = *(const f32x4*)(in + i);
  short4v o;
  o[0] = bfbits(x[0]); o[1] = bfbits(x[1]); o[2] = bfbits(x[2]); o[3] = bfbits(x[3]);
  *(short4v*)((short*)out + i) = o;
}

// ---------------- transpose fp32 [R][C] -> bf16 [C][R] ----------------
__global__ __launch_bounds__(256) void k_transpose_f32_bf16(const float* __restrict__ in,
                                                            bf16_t* __restrict__ out,
                                                            int R, int C) {
  __shared__ float tile[32][33];
  int tx = threadIdx.x & 31, ty = threadIdx.x >> 5;   // 32 x 8
  int r0 = blockIdx.y * 32, c0 = blockIdx.x * 32;
  #pragma unroll
  for (int i = 0; i < 4; ++i)
    tile[ty + i * 8][tx] = in[(size_t)(r0 + ty + i * 8) * C + c0 + tx];
  __syncthreads();
  #pragma unroll
  for (int i = 0; i < 4; ++i)
    out[(size_t)(c0 + ty + i * 8) * R + r0 + tx] = __float2bfloat16(tile[tx][ty + i * 8]);
}

// ---- four square 1024x1024 transposes in one launch (z selects weight) ----
__global__ __launch_bounds__(256) void k_transpose4_f32_bf16(
    const float* __restrict__ w0, const float* __restrict__ w1,
    const float* __restrict__ w2, const float* __restrict__ w3,
    bf16_t* __restrict__ o0, bf16_t* __restrict__ o1,
    bf16_t* __restrict__ o2, bf16_t* __restrict__ o3) {
  __shared__ float tile[32][33];
  const int zz = blockIdx.z;
  const float* in = zz == 0 ? w0 : zz == 1 ? w1 : zz == 2 ? w2 : w3;
  bf16_t* out = zz == 0 ? o0 : zz == 1 ? o1 : zz == 2 ? o2 : o3;
  int tx = threadIdx.x & 31, ty = threadIdx.x >> 5;
  int r0 = blockIdx.y * 32, c0 = blockIdx.x * 32;
  #pragma unroll
  for (int i = 0; i < 4; ++i)
    tile[ty + i * 8][tx] = in[(size_t)(r0 + ty + i * 8) * 1024 + c0 + tx];
  __syncthreads();
  #pragma unroll
  for (int i = 0; i < 4; ++i)
    out[(size_t)(c0 + ty + i * 8) * 1024 + r0 + tx] = __float2bfloat16(tile[tx][ty + i * 8]);
}

// ---------------- batched transpose bf16 [R][C] -> [C][R] ----------------
__global__ __launch_bounds__(256) void k_transpose_bf16_b(const bf16_t* __restrict__ in,
                                                          bf16_t* __restrict__ out,
                                                          int R, int C, long sIn, long sOut) {
  __shared__ bf16_t tile[32][33];
  const bf16_t* inz = in + (size_t)blockIdx.z * sIn;
  bf16_t* outz = out + (size_t)blockIdx.z * sOut;
  int tx = threadIdx.x & 31, ty = threadIdx.x >> 5;
  int r0 = blockIdx.y * 32, c0 = blockIdx.x * 32;
  #pragma unroll
  for (int i = 0; i < 4; ++i)
    tile[ty + i * 8][tx] = inz[(size_t)(r0 + ty + i * 8) * C + c0 + tx];
  __syncthreads();
  #pragma unroll
  for (int i = 0; i < 4; ++i)
    outz[(size_t)(c0 + ty + i * 8) * R + r0 + tx] = tile[tx][ty + i * 8];
}

// ---------------- GEMM: C[M][N] = A[M][K](bf16) @ Bt[N][K](bf16) ----------------
// m97 structure: block 256 thr = 4 waves (2x2), wave tile (BM/2)x(BN/2),
// MFMA 16x16x32, BK=32, LINEAR LDS staged via global_load_lds width 16.
// T1: bijective XCD swizzle of linear block id (REQUIRES grid total %8==0).
// A-frag: A[m=lane&15][k=(lane>>4)*8+j]; C/D: col=lane&15, row=(lane>>4)*4+reg.
// QKV3: Bt is 3 vertically-concatenated [1024][K] weights; output routed to
// Cb + (n0>>10)*4194304 with per-tensor bias; Q (tz==0) pre-scaled by 1/8.
template<int BM, int BN, bool ALPHA, bool BIAS, bool RELU, bool RESID,
         bool OUTF, bool OUTB, bool QKV3>
__global__ __launch_bounds__(256)
void k_gemm_bt(const bf16_t* __restrict__ A, const bf16_t* __restrict__ Bt,
               float* __restrict__ Cf, bf16_t* __restrict__ Cb,
               const float* __restrict__ bias, const float* __restrict__ bias2,
               const float* __restrict__ bias3, const float* __restrict__ resid,
               int Kdim, int lda, int ldb, int ldc, float alpha) {
  constexpr int BK = 32;
  constexpr int WTM = BM / 2, WTN = BN / 2;
  constexpr int MI = WTM / 16, NI = WTN / 16;
  __shared__ __align__(16) bf16_t sA[BM * BK];
  __shared__ __align__(16) bf16_t sB[BN * BK];

  const int tid = threadIdx.x;
  const int lane = tid & 63;
  const int wv = tid >> 6;
  const int wm = wv & 1, wn = wv >> 1;

  // T1 XCD swizzle (bijective since total %8 == 0 for all call sites)
  const int gx = gridDim.x;
  const int total = gx * gridDim.y;
  const int lin = blockIdx.y * gx + blockIdx.x;
  const int swz = (lin & 7) * (total >> 3) + (lin >> 3);
  const size_t m0 = (size_t)(swz / gx) * BM;
  const size_t n0 = (size_t)(swz % gx) * BN;

  f32x4 acc[MI][NI] = {};

  // staging geometry: chunk = 16 rows = 1KB; lane l covers (row l>>2, 16B col l&3)
  const int rr = lane >> 2, cc = (lane & 3) * 8;
  const bf16_t* Arow = A + (m0 + rr) * (size_t)lda + cc;   // + chunk*16*lda + k0
  const bf16_t* Brow = Bt + (n0 + rr) * (size_t)ldb + cc;

  const int fm = wm * WTM + (lane & 15);
  const int fn = wn * WTN + (lane & 15);
  const int fk = (lane >> 4) * 8;

  for (int k0 = 0; k0 < Kdim; k0 += BK) {
    #pragma unroll
    for (int j = 0; j < BM / 64; ++j) {
      int c = j * 4 + wv;                       // chunk id, wave-uniform
      gload_lds16(Arow + (size_t)c * 16 * lda + k0, sA + c * 512);
    }
    #pragma unroll
    for (int j = 0; j < BN / 64; ++j) {
      int c = j * 4 + wv;
      gload_lds16(Brow + (size_t)c * 16 * ldb + k0, sB + c * 512);
    }
    __syncthreads();   // drains vmcnt: LDS tiles complete

    short8 av[MI], bvv[NI];
    #pragma unroll
    for (int mi = 0; mi < MI; ++mi) av[mi] = *(const short8*)(sA + (fm + mi * 16) * BK + fk);
    #pragma unroll
    for (int ni = 0; ni < NI; ++ni) bvv[ni] = *(const short8*)(sB + (fn + ni * 16) * BK + fk);
    #pragma unroll
    for (int mi = 0; mi < MI; ++mi)
      #pragma unroll
      for (int ni = 0; ni < NI; ++ni)
        acc[mi][ni] = __builtin_amdgcn_mfma_f32_16x16x32_bf16(av[mi], bvv[ni],
                                                              acc[mi][ni], 0, 0, 0);
    __syncthreads();
  }

  // epilogue
  const int tz = QKV3 ? (int)(n0 >> 10) : 0;                    // uniform per block
  const float* bp = BIAS ? (QKV3 ? (tz == 0 ? bias : (tz == 1 ? bias2 : bias3))
                                 : bias) : nullptr;
  bf16_t* cb = QKV3 ? (Cb + (size_t)tz * 4194304) : Cb;
  const float qscale = (QKV3 && tz == 0) ? 0.125f : 1.0f;
  const int col0 = (int)n0 + wn * WTN + (lane & 15);
  const int row0 = (int)m0 + wm * WTM + ((lane >> 4) << 2);
  #pragma unroll
  for (int ni = 0; ni < NI; ++ni) {
    const int col = col0 + ni * 16;
    const int colw = QKV3 ? (col & 1023) : col;
    const float bval = BIAS ? bp[colw] : 0.0f;
    #pragma unroll
    for (int mi = 0; mi < MI; ++mi) {
      #pragma unroll
      for (int r = 0; r < 4; ++r) {
        int row = row0 + mi * 16 + r;
        float v = acc[mi][ni][r];
        if (ALPHA) v *= alpha;
        v += bval;
        if (QKV3) v *= qscale;
        size_t off = (size_t)row * ldc + colw;
        if (RESID) v += resid[off];
        if (RELU) v = fmaxf(v, 0.0f);
        if (OUTF) Cf[off] = v;
        if (OUTB) cb[off] = __float2bfloat16(v);
      }
    }
  }
}

// ---------------- fused attention, BARRIER-FREE: S=(Q/8)@K^T, softmax (exact,
// written to attn), ctx = P @ V. ONE WAVE per block owning 32 Q-rows of one
// head; 2048 independent blocks. K/V fragments read DIRECT from global
// (L2-resident: head-grouped XCD swizzle keeps each head's 256KB K/V on one
// XCD). Two passes (per-lane online stats; recompute S). K frags
// double-buffered in regs (kfA/kfB, static idx); V issued early per chunk.
// Only LDS: wave-private sP[32][64] (XOR-swizzled), intra-wave lgkmcnt fence.
// Q,K: [64][1024][64] bf16. Vt: [64][64][1024] bf16. attn: [64][1024][1024]
// fp32 (nontemporal). ctx: [64][1024][64] bf16.
__global__ __launch_bounds__(64) void k_flash_attn(const bf16_t* __restrict__ Qb,
                                                   const bf16_t* __restrict__ Kb,
                                                   const bf16_t* __restrict__ Vt,
                                                   float* __restrict__ attn,
                                                   bf16_t* __restrict__ ctx) {
  __shared__ __align__(16) bf16_t sP[32][64];

  const int lane = threadIdx.x;       // one wave

  // XCD swizzle: 2048 blocks; XCD k gets swz k*256..k*256+255 = heads k*8..k*8+7.
  const int lin = blockIdx.x;
  const int swz = (lin & 7) * 256 + (lin >> 3);
  const int z = swz >> 5;             // head
  const int m0 = (swz & 31) * 32;     // 32-row strip within head

  const bf16_t* Qz = Qb + (size_t)z * 65536;
  const bf16_t* Kz = Kb + (size_t)z * 65536;
  const bf16_t* Vz = Vt + (size_t)z * 65536;
  float* az = attn + (size_t)z * 1048576;
  bf16_t* cz = ctx + (size_t)z * 65536;

  const int fr = lane & 15;           // frag row/col index
  const int fk = (lane >> 4) * 8;     // frag k offset
  const int crow = (lane >> 4) << 2;  // C/D row base
  const int rko = (fr & 7) << 3;      // sP read-side XOR

  // Q A-frags from global (one-time; Q pre-scaled by 1/8 upstream)
  short8 qf[2][2];
  #pragma unroll
  for (int mi = 0; mi < 2; ++mi)
    #pragma unroll
    for (int ks = 0; ks < 2; ++ks)
      qf[mi][ks] = *(const short8*)(Qz + (size_t)(m0 + mi * 16 + fr) * 64 + ks * 32 + fk);

  // K frags for chunk c: kf[ni][ks] = K[c*64 + ni*16 + fr][ks*32 + fk .. +7]
  const bf16_t* kbase = Kz + (size_t)fr * 64 + fk;
  auto loadK = [&](short8 (&kf)[4][2], int c) {
    const bf16_t* b = kbase + (size_t)c * 4096;
    #pragma unroll
    for (int ni = 0; ni < 4; ++ni)
      #pragma unroll
      for (int ks = 0; ks < 2; ++ks)
        kf[ni][ks] = *(const short8*)(b + ni * 1024 + ks * 32);
  };
  // V frags for chunk c: vf[ni][ks] = Vt[ni*16 + fr][c*64 + ks*32 + fk .. +7]
  const bf16_t* vbase = Vz + (size_t)fr * 1024 + fk;
  auto loadV = [&](short8 (&vf)[4][2], int c) {
    const bf16_t* b = vbase + c * 64;
    #pragma unroll
    for (int ni = 0; ni < 4; ++ni)
      #pragma unroll
      for (int ks = 0; ks < 2; ++ks)
        vf[ni][ks] = *(const short8*)(b + (size_t)ni * 16 * 1024 + ks * 32);
  };

  float m_ln[2][4], s_ln[2][4];       // per-lane online stats
  #pragma unroll
  for (int mi = 0; mi < 2; ++mi)
    #pragma unroll
    for (int r = 0; r < 4; ++r) { m_ln[mi][r] = -1e30f; s_ln[mi][r] = 0.0f; }

  auto qk_stats = [&](short8 (&kf)[4][2]) {
    f32x4 acc[2][4] = {};
    #pragma unroll
    for (int ks = 0; ks < 2; ++ks)
      #pragma unroll
      for (int mi = 0; mi < 2; ++mi)
        #pragma unroll
        for (int ni = 0; ni < 4; ++ni)
          acc[mi][ni] = __builtin_amdgcn_mfma_f32_16x16x32_bf16(qf[mi][ks], kf[ni][ks],
                                                                acc[mi][ni], 0, 0, 0);
    #pragma unroll
    for (int mi = 0; mi < 2; ++mi)
      #pragma unroll
      for (int r = 0; r < 4; ++r) {
        float cm = fmaxf(fmaxf(acc[mi][0][r], acc[mi][1][r]),
                         fmaxf(acc[mi][2][r], acc[mi][3][r]));
        float mo = m_ln[mi][r];
        float mn = fmaxf(mo, cm);
        float se = 0.0f;
        #pragma unroll
        for (int ni = 0; ni < 4; ++ni) se += __expf(acc[mi][ni][r] - mn);
        s_ln[mi][r] = s_ln[mi][r] * __expf(mo - mn) + se;
        m_ln[mi][r] = mn;
      }
  };

  short8 kfA[4][2], kfB[4][2];

  // ---- pass 1: per-lane online max/sum-exp, no sync at all ----
  loadK(kfA, 0);
  for (int c = 0; c < 16; c += 2) {
    loadK(kfB, c + 1);
    qk_stats(kfA);
    if (c + 2 < 16) loadK(kfA, c + 2);
    qk_stats(kfB);
  }

  // one cross-lane merge over the 16-lane fr group (log-sum-exp combine)
  float m_run[2][4], inv_s[2][4];
  #pragma unroll
  for (int mi = 0; mi < 2; ++mi)
    #pragma unroll
    for (int r = 0; r < 4; ++r) {
      float m = m_ln[mi][r], s = s_ln[mi][r];
      #pragma unroll
      for (int o = 1; o < 16; o <<= 1) {
        float m2 = __shfl_xor(m, o, 64);
        float s2 = __shfl_xor(s, o, 64);
        float mn = fmaxf(m, m2);
        s = s * __expf(m - mn) + s2 * __expf(m2 - mn);
        m = mn;
      }
      m_run[mi][r] = m;
      inv_s[mi][r] = 1.0f / s;
    }

  // ---- pass 2: recompute S, emit exact softmax to attn, accumulate P@V ----
  f32x4 cacc[2][4] = {};
  auto emit_pv = [&](short8 (&kf)[4][2], int c) {
    short8 vf[4][2];
    loadV(vf, c);                     // issued early; consumed after emit phase
    f32x4 acc[2][4] = {};
    #pragma unroll
    for (int ks = 0; ks < 2; ++ks)
      #pragma unroll
      for (int mi = 0; mi < 2; ++mi)
        #pragma unroll
        for (int ni = 0; ni < 4; ++ni)
          acc[mi][ni] = __builtin_amdgcn_mfma_f32_16x16x32_bf16(qf[mi][ks], kf[ni][ks],
                                                                acc[mi][ni], 0, 0, 0);
    // normalized P: nontemporal global write (mandatory output) + bf16 to sP
    #pragma unroll
    for (int mi = 0; mi < 2; ++mi)
      #pragma unroll
      for (int ni = 0; ni < 4; ++ni)
        #pragma unroll
        for (int r = 0; r < 4; ++r) {
          int rw = mi * 16 + crow + r;
          float p = __expf(acc[mi][ni][r] - m_run[mi][r]) * inv_s[mi][r];
          __builtin_nontemporal_store(p, &az[(size_t)(m0 + rw) * 1024 + c * 64 + ni * 16 + fr]);
          sP[rw][(ni * 16 + fr) ^ (((crow + r) & 7) << 3)] = __float2bfloat16(p);
        }
    // intra-wave ordering only: wait ds_writes, stop hoisting of sP reads (rule #18)
    asm volatile("s_waitcnt lgkmcnt(0)" ::: "memory");
    __builtin_amdgcn_sched_barrier(0);
    #pragma unroll
    for (int ks = 0; ks < 2; ++ks) {
      short8 pa[2];
      #pragma unroll
      for (int mi = 0; mi < 2; ++mi)
        pa[mi] = *(const short8*)(&sP[mi * 16 + fr][(ks * 32 + fk) ^ rko]);
      #pragma unroll
      for (int mi = 0; mi < 2; ++mi)
        #pragma unroll
        for (int ni = 0; ni < 4; ++ni)
          cacc[mi][ni] = __builtin_amdgcn_mfma_f32_16x16x32_bf16(pa[mi], vf[ni][ks],
                                                                 cacc[mi][ni], 0, 0, 0);
    }
  };

  loadK(kfA, 0);
  for (int c = 0; c < 16; c += 2) {
    loadK(kfB, c + 1);
    emit_pv(kfA, c);
    if (c + 2 < 16) loadK(kfA, c + 2);
    emit_pv(kfB, c + 1);
  }

  // ctx write: [1024][64] bf16 per head
  #pragma unroll
  for (int mi = 0; mi < 2; ++mi)
    #pragma unroll
    for (int ni = 0; ni < 4; ++ni)
      #pragma unroll
      for (int r = 0; r < 4; ++r) {
        int rw = mi * 16 + crow + r;
        cz[(size_t)(m0 + rw) * 64 + ni * 16 + fr] = __float2bfloat16(cacc[mi][ni][r]);
      }
}

// ---------------- row layernorm, width 1024, in place (+optional bf16 copy) -------
__global__ __launch_bounds__(256) void k_layernorm(float* __restrict__ io,
                                                   bf16_t* __restrict__ ob,
                                                   const float* __restrict__ g,
                                                   const float* __restrict__ bta) {
  float* r = io + (size_t)blockIdx.x * 1024;
  const int t = threadIdx.x;
  f32x4 x = *(const f32x4*)(r + t * 4);
  float s = x[0] + x[1] + x[2] + x[3];
  float s2 = x[0] * x[0] + x[1] * x[1] + x[2] * x[2] + x[3] * x[3];
  #pragma unroll
  for (int o = 32; o > 0; o >>= 1) { s += __shfl_xor(s, o, 64); s2 += __shfl_xor(s2, o, 64); }
  __shared__ float as[4], as2[4];
  if ((t & 63) == 0) { as[t >> 6] = s; as2[t >> 6] = s2; }
  __syncthreads();
  s = as[0] + as[1] + as[2] + as[3];
  s2 = as2[0] + as2[1] + as2[2] + as2[3];
  float mu = s * (1.0f / 1024.0f);
  float var = s2 * (1.0f / 1024.0f) - mu * mu;
  float rs = rsqrtf(var + 1e-5f);
  f32x4 gg = *(const f32x4*)(g + t * 4);
  f32x4 bb = *(const f32x4*)(bta + t * 4);
  f32x4 y;
  #pragma unroll
  for (int i = 0; i < 4; ++i) y[i] = (x[i] - mu) * rs * gg[i] + bb[i];
  *(f32x4*)(r + t * 4) = y;
  if (ob) {
    short4v o4;
    o4[0] = bfbits(y[0]); o4[1] = bfbits(y[1]); o4[2] = bfbits(y[2]); o4[3] = bfbits(y[3]);
    *(short4v*)((short*)ob + (size_t)blockIdx.x * 1024 + t * 4) = o4;
  }
}

extern "C" void kernel_launch(void* const* d_in, const int* in_sizes, int n_in,
                              void* d_out, int out_size, void* d_ws, size_t ws_size,
                              hipStream_t stream) {
  (void)in_sizes; (void)n_in; (void)out_size;
  const float* inputs = (const float*)d_in[0];
  const float* Wq = (const float*)d_in[1];  const float* bq = (const float*)d_in[2];
  const float* Wk = (const float*)d_in[3];  const float* bk = (const float*)d_in[4];
  const float* Wv = (const float*)d_in[5];  const float* bv = (const float*)d_in[6];
  const float* Wo = (const float*)d_in[7];  const float* bo = (const float*)d_in[8];
  const float* ln1g = (const float*)d_in[9];  const float* ln1b = (const float*)d_in[10];
  const float* W1 = (const float*)d_in[11]; const float* b1 = (const float*)d_in[12];
  const float* W2 = (const float*)d_in[13]; const float* b2 = (const float*)d_in[14];
  const float* ln2g = (const float*)d_in[15]; const float* ln2b = (const float*)d_in[16];

  const size_t MB = 1ull << 20;
  if (ws_size < 96 * MB) return;  // layout below needs 96 MB scratch

  char* ws = (char*)d_ws;
  bf16_t* WQT  = (bf16_t*)(ws + 0 * MB);   // [1024][1024]; WQT/WKT/WVT contiguous
  bf16_t* WKT  = (bf16_t*)(ws + 2 * MB);   //   -> fused QKV sees [3072][1024]
  bf16_t* WVT  = (bf16_t*)(ws + 4 * MB);
  bf16_t* WOT  = (bf16_t*)(ws + 6 * MB);
  bf16_t* W1T  = (bf16_t*)(ws + 8 * MB);   // [4096][1024]
  bf16_t* W2T  = (bf16_t*)(ws + 16 * MB);  // [1024][4096]
  bf16_t* XB   = (bf16_t*)(ws + 24 * MB);  // [4096][1024]; dead after QKV
  bf16_t* QB   = (bf16_t*)(ws + 32 * MB);  // QB/KB/VB contiguous, 8MB stride
  bf16_t* KB   = (bf16_t*)(ws + 40 * MB);
  bf16_t* VB   = (bf16_t*)(ws + 48 * MB);  // dead after Vt transpose
  bf16_t* VT   = (bf16_t*)(ws + 56 * MB);  // [64 batches][64][1024]; dead after flash
  bf16_t* CTX  = (bf16_t*)(ws + 24 * MB);  // reuse XB slot
  float*  OUT1F = (float*)(ws + 40 * MB);  // fp32 [4096][1024] (reuse KB+VB slots)
  bf16_t* OUT1B = (bf16_t*)(ws + 32 * MB); // reuse QB slot
  bf16_t* HB   = (bf16_t*)(ws + 64 * MB);  // [4096][4096]

  float* outF = (float*)d_out;             // [4096][1024]
  float* attn = outF + 4194304;            // [64][1024][1024] fp32 (final output region)

  // --- prep: bf16 input copy + transposed bf16 weights ---
  k_f32_to_bf16<<<4096, 256, 0, stream>>>(inputs, XB);
  k_transpose4_f32_bf16<<<dim3(32, 32, 4), 256, 0, stream>>>(Wq, Wk, Wv, Wo,
                                                             WQT, WKT, WVT, WOT);
  k_transpose_f32_bf16<<<dim3(128, 32), 256, 0, stream>>>(W1, W1T, 1024, 4096);
  k_transpose_f32_bf16<<<dim3(32, 128), 256, 0, stream>>>(W2, W2T, 4096, 1024);

  // --- fused QKV: [4096,1024] @ [1024,3072] -> QB/KB/VB (Q pre-scaled 1/8) ---
  k_gemm_bt<128, 128, false, true, false, false, false, true, true>
      <<<dim3(24, 32), 256, 0, stream>>>(XB, WQT, nullptr, QB, bq, bk, bv, nullptr,
                                         1024, 1024, 1024, 1024, 1.0f);

  // --- per-"head" V transpose: [1024][64] -> [64][1024], 64 batches ---
  k_transpose_bf16_b<<<dim3(2, 32, 64), 256, 0, stream>>>(VB, VT, 1024, 64, 65536, 65536);

  // --- fused scores+softmax+PV; writes exact attn fp32 + ctx bf16 ---
  k_flash_attn<<<2048, 64, 0, stream>>>(QB, KB, VT, attn, CTX);

  // --- out-proj + bias + residual(inputs) -> OUT1F fp32 (BN=64: 512 blocks) ---
  k_gemm_bt<128, 64, false, true, false, true, true, false, false>
      <<<dim3(16, 32), 256, 0, stream>>>(CTX, WOT, OUT1F, nullptr, bo, nullptr, nullptr,
                                         inputs, 1024, 1024, 1024, 1024, 1.0f);

  // --- LN1 in place + bf16 copy ---
  k_layernorm<<<4096, 256, 0, stream>>>(OUT1F, OUT1B, ln1g, ln1b);

  // --- FFN1: relu(out1 @ W1 + b1) -> HB bf16 [4096][4096] ---
  k_gemm_bt<128, 128, false, true, true, false, false, true, false>
      <<<dim3(32, 32), 256, 0, stream>>>(OUT1B, W1T, nullptr, HB, b1, nullptr, nullptr,
                                         nullptr, 1024, 1024, 1024, 4096, 1.0f);

  // --- FFN2: HB @ W2 + b2 + out1 -> d_out[0:4M] fp32 (BN=64: 512 blocks) ---
  k_gemm_bt<128, 64, false, true, false, true, true, false, false>
      <<<dim3(16, 32), 256, 0, stream>>>(HB, W2T, outF, nullptr, b2, nullptr, nullptr,
                                         OUT1F, 4096, 4096, 4096, 1024, 1.0f);

  // --- LN2 in place on d_out ---
  k_layernorm<<<4096, 256, 0, stream>>>(outF, nullptr, ln2g, ln2b);
}